// Round 13
// baseline (844.666 us; speedup 1.0000x reference)
//
#include <hip/hip_runtime.h>
#include <hip/hip_bf16.h>

// GCNEncoder: 2x GCNConv(64->64) + BatchNorm + ELU + global_mean_pool
// N=50000, E=800000, D=64, G=64. Inputs f32/int32. OUTPUT IS FLOAT32
// (established R12: harness decodes d_out as f32; bf16 writes were the sole
// bug in the R1-R7 faithful pipelines). Layout: [N*64] node feats, [G*64] pool.

constexpr int GGRAPHS = 64;

__global__ void deg_cnt_kernel(const int* __restrict__ dst, const int* __restrict__ batch,
                               float* __restrict__ deg, float* __restrict__ cnt,
                               int E, int n) {
  int i = blockIdx.x * 256 + threadIdx.x;
  if (i < E) {
    int d = dst[i];
    if ((unsigned)d < (unsigned)n) atomicAdd(&deg[d], 1.0f);
  }
  if (i < n) {
    int g = batch[i];
    if ((unsigned)g < (unsigned)GGRAPHS) atomicAdd(&cnt[g], 1.0f);
  }
}

__global__ void dinv_kernel(float* __restrict__ deg_dinv, int n) {
  int i = blockIdx.x * 256 + threadIdx.x;
  if (i < n) deg_dinv[i] = rsqrtf(deg_dinv[i] + 1.0f);
}

// Y[n,64] = X[n,64] @ W[64,64]; block = 4 rows x 64 cols
__global__ void mm64_kernel(const float* __restrict__ X, const float* __restrict__ W,
                            float* __restrict__ Y, int n) {
  __shared__ float Ws[64][64];
  __shared__ float xs[4][64];
  int tid = threadIdx.x;
  for (int i = tid; i < 64 * 64; i += 256) Ws[i >> 6][i & 63] = W[i];
  int rr = tid >> 6, c = tid & 63;
  int row = blockIdx.x * 4 + rr;
  xs[rr][c] = (row < n) ? X[row * 64 + c] : 0.0f;
  __syncthreads();
  float acc = 0.0f;
#pragma unroll
  for (int k = 0; k < 64; ++k) acc = fmaf(xs[rr][k], Ws[k][c], acc);
  if (row < n) Y[row * 64 + c] = acc;
}

// BN affine + ELU on X rows, then @W
__global__ void bn_elu_mm64_kernel(const float* __restrict__ X, const float* __restrict__ W,
                                   const float* __restrict__ ss, float* __restrict__ Y, int n) {
  __shared__ float Ws[64][64];
  __shared__ float xs[4][64];
  int tid = threadIdx.x;
  for (int i = tid; i < 64 * 64; i += 256) Ws[i >> 6][i & 63] = W[i];
  int rr = tid >> 6, c = tid & 63;
  int row = blockIdx.x * 4 + rr;
  float v = 0.0f;
  if (row < n) {
    v = X[row * 64 + c] * ss[c] + ss[64 + c];
    v = v > 0.0f ? v : expm1f(v);
  }
  xs[rr][c] = v;
  __syncthreads();
  float acc = 0.0f;
#pragma unroll
  for (int k = 0; k < 64; ++k) acc = fmaf(xs[rr][k], Ws[k][c], acc);
  if (row < n) Y[row * 64 + c] = acc;
}

// one wave per edge (64 lanes = 64 channels): AGG[dst] += H[src]*dinv[src]*dinv[dst]
__global__ void edge_scatter_kernel(const int* __restrict__ src, const int* __restrict__ dst,
                                    const float* __restrict__ dinv, const float* __restrict__ H,
                                    float* __restrict__ AGG, int E, int n) {
  int gid = blockIdx.x * 256 + threadIdx.x;
  int e = gid >> 6;
  int ch = gid & 63;
  if (e >= E) return;
  int s = src[e], d = dst[e];
  if ((unsigned)s >= (unsigned)n || (unsigned)d >= (unsigned)n) return;
  float c = dinv[s] * dinv[d];
  atomicAdd(&AGG[d * 64 + ch], H[s * 64 + ch] * c);
}

// AGG[i] += H1[i]*dinv[i]^2 + b1 (in place), plus per-channel sum/sumsq
__global__ void selfloop_bias_bnstats_kernel(const float* __restrict__ H1,
                                             const float* __restrict__ dinv,
                                             const float* __restrict__ b1,
                                             float* __restrict__ AGG,
                                             float* __restrict__ bns, int n) {
  int tid = threadIdx.x;
  int ch = tid & 63;
  float bias = b1[ch];
  float s = 0.0f, s2 = 0.0f;
  int total = n * 64;
  for (int idx = blockIdx.x * 256 + tid; idx < total; idx += 512 * 256) {
    int i = idx >> 6;
    float di = dinv[i];
    float v = AGG[idx] + H1[idx] * di * di + bias;
    AGG[idx] = v;
    s += v;
    s2 += v * v;
  }
  __shared__ float ls[256], ls2[256];
  ls[tid] = s;
  ls2[tid] = s2;
  __syncthreads();
  if (tid < 64) {
    s = ls[tid] + ls[tid + 64] + ls[tid + 128] + ls[tid + 192];
    s2 = ls2[tid] + ls2[tid + 64] + ls2[tid + 128] + ls2[tid + 192];
    atomicAdd(&bns[ch], s);
    atomicAdd(&bns[64 + ch], s2);
  }
}

__global__ void bn_final_kernel(const float* __restrict__ bns, const float* __restrict__ gamma,
                                const float* __restrict__ beta, float* __restrict__ ss, int n) {
  int ch = threadIdx.x;  // 64 threads
  float inv_n = 1.0f / (float)n;
  float mu = bns[ch] * inv_n;
  float var = bns[64 + ch] * inv_n - mu * mu;
  var = fmaxf(var, 0.0f);
  float sc = gamma[ch] * rsqrtf(var + 1e-5f);
  ss[ch] = sc;
  ss[64 + ch] = beta[ch] - mu * sc;
}

// out = AGG2 + H2*dinv^2 + b2 -> f32; pool[batch[i]] += out
__global__ void out_pool_kernel(const float* __restrict__ H2, const float* __restrict__ AGG2,
                                const float* __restrict__ dinv, const float* __restrict__ b2,
                                const int* __restrict__ batch, float* __restrict__ pool,
                                float* __restrict__ out, int n) {
  int idx = blockIdx.x * 256 + threadIdx.x;
  if (idx >= n * 64) return;
  int i = idx >> 6;
  int ch = idx & 63;
  float di = dinv[i];
  float o = AGG2[idx] + H2[idx] * di * di + b2[ch];
  out[idx] = o;
  int g = batch[i];
  if ((unsigned)g < (unsigned)GGRAPHS) atomicAdd(&pool[g * 64 + ch], o);
}

__global__ void pool_final_kernel(const float* __restrict__ pool, const float* __restrict__ cnt,
                                  float* __restrict__ out) {
  int idx = blockIdx.x * 256 + threadIdx.x;  // 4096 total
  int g = idx >> 6;
  out[idx] = pool[idx] / fmaxf(cnt[g], 1.0f);
}

extern "C" void kernel_launch(void* const* d_in, const int* in_sizes, int n_in,
                              void* d_out, int out_size, void* d_ws, size_t ws_size,
                              hipStream_t stream) {
  const float* x = (const float*)d_in[0];
  const int* ei = (const int*)d_in[1];
  const int* batch = (const int*)d_in[2];
  const float* W1 = (const float*)d_in[3];
  const float* b1 = (const float*)d_in[4];
  const float* gamma = (const float*)d_in[5];
  const float* beta = (const float*)d_in[6];
  const float* W2 = (const float*)d_in[7];
  const float* b2 = (const float*)d_in[8];

  const int n = in_sizes[0] / 64;
  const int E = in_sizes[1] / 2;
  const int* src = ei;
  const int* dstp = ei + E;

  float* ws = (float*)d_ws;
  size_t nf = (size_t)n * 64;
  float* bufA = ws;            // h1, then h2
  float* bufB = ws + nf;       // agg1 / pre-BN h, then agg2
  float* dinv = ws + 2 * nf;   // n floats (deg then rsqrt)
  float* bns = dinv + n;       // 128: sum, sumsq
  float* ss = bns + 128;       // 128: scale, shift
  float* cnt = ss + 128;       // 64
  float* pool = cnt + 64;      // 64*64

  float* out = (float*)d_out;  // FLOAT32 output (R12 finding)

  // zero bufB .. pool end in one shot (covers agg1, deg, bns, ss, cnt, pool)
  size_t zbytes = (size_t)((char*)(pool + GGRAPHS * 64) - (char*)bufB);
  hipMemsetAsync(bufB, 0, zbytes, stream);

  int blk = 256;
  int gridE = (E + blk - 1) / blk;
  int gridN = (n + blk - 1) / blk;
  int gridRows = (n + 3) / 4;
  int gridEdgeCh = (int)(((long long)E * 64 + blk - 1) / blk);
  int gridNodeCh = (int)(((long long)n * 64 + blk - 1) / blk);

  deg_cnt_kernel<<<gridE, blk, 0, stream>>>(dstp, batch, dinv, cnt, E, n);
  dinv_kernel<<<gridN, blk, 0, stream>>>(dinv, n);
  mm64_kernel<<<gridRows, blk, 0, stream>>>(x, W1, bufA, n);
  edge_scatter_kernel<<<gridEdgeCh, blk, 0, stream>>>(src, dstp, dinv, bufA, bufB, E, n);
  selfloop_bias_bnstats_kernel<<<512, blk, 0, stream>>>(bufA, dinv, b1, bufB, bns, n);
  bn_final_kernel<<<1, 64, 0, stream>>>(bns, gamma, beta, ss, n);
  bn_elu_mm64_kernel<<<gridRows, blk, 0, stream>>>(bufB, W2, ss, bufA, n);
  hipMemsetAsync(bufB, 0, nf * sizeof(float), stream);
  edge_scatter_kernel<<<gridEdgeCh, blk, 0, stream>>>(src, dstp, dinv, bufA, bufB, E, n);
  out_pool_kernel<<<gridNodeCh, blk, 0, stream>>>(bufA, bufB, dinv, b2, batch, pool, out, n);
  pool_final_kernel<<<(GGRAPHS * 64) / blk, blk, 0, stream>>>(pool, cnt, out + nf);
}

// Round 14
// 571.054 us; speedup vs baseline: 1.4791x; 1.4791x over previous
//
#include <hip/hip_runtime.h>

// GCNEncoder: 2x GCNConv(64->64) + BatchNorm + ELU + global_mean_pool
// N=50000, E=800000, D=64, G=64. Inputs f32/int32, output f32 (R12 finding).
// R13 baseline 844.7us; deg_cnt=269us (atomic contention on sorted batch).
// R14: split deg (int atomics) / cnt (LDS histogram); LDS-reduced out_pool.

constexpr int GGRAPHS = 64;

// deg[i] = # edges with dst==i (scattered int atomics; measures the atomic wall)
__global__ void deg_kernel(const int* __restrict__ dst, int* __restrict__ deg, int E, int n) {
  int i = blockIdx.x * 256 + threadIdx.x;
  if (i < E) {
    int d = dst[i];
    if ((unsigned)d < (unsigned)n) atomicAdd(&deg[d], 1);
  }
}

// cnt[g] via per-block LDS histogram (batch sorted -> same-bin storms stay in LDS)
__global__ void cnt_kernel(const int* __restrict__ batch, int* __restrict__ cnt, int n) {
  __shared__ int h[GGRAPHS];
  int t = threadIdx.x;
  if (t < GGRAPHS) h[t] = 0;
  __syncthreads();
  for (int i = blockIdx.x * 256 + t; i < n; i += gridDim.x * 256) {
    int g = batch[i];
    if ((unsigned)g < (unsigned)GGRAPHS) atomicAdd(&h[g], 1);
  }
  __syncthreads();
  if (t < GGRAPHS && h[t] > 0) atomicAdd(&cnt[t], h[t]);
}

// in-place: int deg -> float rsqrt(deg+1)
__global__ void dinv_kernel(int* __restrict__ buf, int n) {
  int i = blockIdx.x * 256 + threadIdx.x;
  if (i < n) {
    int d = buf[i];
    ((float*)buf)[i] = rsqrtf((float)d + 1.0f);
  }
}

// Y[n,64] = X[n,64] @ W[64,64]; block = 4 rows x 64 cols
__global__ void mm64_kernel(const float* __restrict__ X, const float* __restrict__ W,
                            float* __restrict__ Y, int n) {
  __shared__ float Ws[64][64];
  __shared__ float xs[4][64];
  int tid = threadIdx.x;
  for (int i = tid; i < 64 * 64; i += 256) Ws[i >> 6][i & 63] = W[i];
  int rr = tid >> 6, c = tid & 63;
  int row = blockIdx.x * 4 + rr;
  xs[rr][c] = (row < n) ? X[row * 64 + c] : 0.0f;
  __syncthreads();
  float acc = 0.0f;
#pragma unroll
  for (int k = 0; k < 64; ++k) acc = fmaf(xs[rr][k], Ws[k][c], acc);
  if (row < n) Y[row * 64 + c] = acc;
}

// BN affine + ELU on X rows, then @W
__global__ void bn_elu_mm64_kernel(const float* __restrict__ X, const float* __restrict__ W,
                                   const float* __restrict__ ss, float* __restrict__ Y, int n) {
  __shared__ float Ws[64][64];
  __shared__ float xs[4][64];
  int tid = threadIdx.x;
  for (int i = tid; i < 64 * 64; i += 256) Ws[i >> 6][i & 63] = W[i];
  int rr = tid >> 6, c = tid & 63;
  int row = blockIdx.x * 4 + rr;
  float v = 0.0f;
  if (row < n) {
    v = X[row * 64 + c] * ss[c] + ss[64 + c];
    v = v > 0.0f ? v : expm1f(v);
  }
  xs[rr][c] = v;
  __syncthreads();
  float acc = 0.0f;
#pragma unroll
  for (int k = 0; k < 64; ++k) acc = fmaf(xs[rr][k], Ws[k][c], acc);
  if (row < n) Y[row * 64 + c] = acc;
}

// one wave per edge (64 lanes = 64 channels): AGG[dst] += H[src]*dinv[src]*dinv[dst]
__global__ void edge_scatter_kernel(const int* __restrict__ src, const int* __restrict__ dst,
                                    const float* __restrict__ dinv, const float* __restrict__ H,
                                    float* __restrict__ AGG, int E, int n) {
  int gid = blockIdx.x * 256 + threadIdx.x;
  int e = gid >> 6;
  int ch = gid & 63;
  if (e >= E) return;
  int s = src[e], d = dst[e];
  if ((unsigned)s >= (unsigned)n || (unsigned)d >= (unsigned)n) return;
  float c = dinv[s] * dinv[d];
  atomicAdd(&AGG[d * 64 + ch], H[s * 64 + ch] * c);
}

// AGG[i] += H1[i]*dinv[i]^2 + b1 (in place), plus per-channel sum/sumsq
__global__ void selfloop_bias_bnstats_kernel(const float* __restrict__ H1,
                                             const float* __restrict__ dinv,
                                             const float* __restrict__ b1,
                                             float* __restrict__ AGG,
                                             float* __restrict__ bns, int n) {
  int tid = threadIdx.x;
  int ch = tid & 63;
  float bias = b1[ch];
  float s = 0.0f, s2 = 0.0f;
  int total = n * 64;
  for (int idx = blockIdx.x * 256 + tid; idx < total; idx += 512 * 256) {
    int i = idx >> 6;
    float di = dinv[i];
    float v = AGG[idx] + H1[idx] * di * di + bias;
    AGG[idx] = v;
    s += v;
    s2 += v * v;
  }
  __shared__ float ls[256], ls2[256];
  ls[tid] = s;
  ls2[tid] = s2;
  __syncthreads();
  if (tid < 64) {
    s = ls[tid] + ls[tid + 64] + ls[tid + 128] + ls[tid + 192];
    s2 = ls2[tid] + ls2[tid + 64] + ls2[tid + 128] + ls2[tid + 192];
    atomicAdd(&bns[ch], s);
    atomicAdd(&bns[64 + ch], s2);
  }
}

__global__ void bn_final_kernel(const float* __restrict__ bns, const float* __restrict__ gamma,
                                const float* __restrict__ beta, float* __restrict__ ss, int n) {
  int ch = threadIdx.x;  // 64 threads
  float inv_n = 1.0f / (float)n;
  float mu = bns[ch] * inv_n;
  float var = bns[64 + ch] * inv_n - mu * mu;
  var = fmaxf(var, 0.0f);
  float sc = gamma[ch] * rsqrtf(var + 1e-5f);
  ss[ch] = sc;
  ss[64 + ch] = beta[ch] - mu * sc;
}

// out = AGG2 + H2*dinv^2 + b2 -> f32; pool via per-block LDS reduction.
// Block = 64 rows x 64 ch (4 row-groups of 16 rows per thread-group).
// Sorted batch -> block spans <=2 graphs almost surely; rare middles fall back.
__global__ void out_pool_kernel(const float* __restrict__ H2, const float* __restrict__ AGG2,
                                const float* __restrict__ dinv, const float* __restrict__ b2,
                                const int* __restrict__ batch, float* __restrict__ pool,
                                float* __restrict__ out, int n) {
  __shared__ float a0[256], a1[256];
  int t = threadIdx.x;
  int ch = t & 63;
  int grp = t >> 6;  // 4 groups x 16 rows
  int base = blockIdx.x * 64;
  int lastrow = base + 63 < n - 1 ? base + 63 : n - 1;
  int g0 = batch[base < n ? base : n - 1];
  int glast = batch[lastrow];
  float bias = b2[ch];
  float s0 = 0.0f, s1 = 0.0f;
  for (int k = 0; k < 16; ++k) {
    int row = base + grp * 16 + k;
    if (row >= n) break;
    float di = dinv[row];
    int idx = row * 64 + ch;
    float o = AGG2[idx] + H2[idx] * di * di + bias;
    out[idx] = o;
    int g = batch[row];
    if (g == g0) s0 += o;
    else if (g == glast) s1 += o;
    else if ((unsigned)g < (unsigned)GGRAPHS) atomicAdd(&pool[g * 64 + ch], o);
  }
  a0[t] = s0;
  a1[t] = s1;
  __syncthreads();
  if (t < 64) {  // t == ch here
    float r0 = a0[t] + a0[t + 64] + a0[t + 128] + a0[t + 192];
    if ((unsigned)g0 < (unsigned)GGRAPHS) atomicAdd(&pool[g0 * 64 + t], r0);
    if (glast != g0) {
      float r1 = a1[t] + a1[t + 64] + a1[t + 128] + a1[t + 192];
      if ((unsigned)glast < (unsigned)GGRAPHS) atomicAdd(&pool[glast * 64 + t], r1);
    }
  }
}

__global__ void pool_final_kernel(const float* __restrict__ pool, const int* __restrict__ cnt,
                                  float* __restrict__ out) {
  int idx = blockIdx.x * 256 + threadIdx.x;  // 4096 total
  int g = idx >> 6;
  float c = (float)cnt[g];
  out[idx] = pool[idx] / fmaxf(c, 1.0f);
}

extern "C" void kernel_launch(void* const* d_in, const int* in_sizes, int n_in,
                              void* d_out, int out_size, void* d_ws, size_t ws_size,
                              hipStream_t stream) {
  const float* x = (const float*)d_in[0];
  const int* ei = (const int*)d_in[1];
  const int* batch = (const int*)d_in[2];
  const float* W1 = (const float*)d_in[3];
  const float* b1 = (const float*)d_in[4];
  const float* gamma = (const float*)d_in[5];
  const float* beta = (const float*)d_in[6];
  const float* W2 = (const float*)d_in[7];
  const float* b2 = (const float*)d_in[8];

  const int n = in_sizes[0] / 64;
  const int E = in_sizes[1] / 2;
  const int* src = ei;
  const int* dstp = ei + E;

  float* ws = (float*)d_ws;
  size_t nf = (size_t)n * 64;
  float* bufA = ws;            // h1, then h2
  float* bufB = ws + nf;       // agg1 / pre-BN h, then agg2
  float* dinv = ws + 2 * nf;   // n floats (int deg, then in-place rsqrt)
  float* bns = dinv + n;       // 128: sum, sumsq
  float* ss = bns + 128;       // 128: scale, shift
  int* cnt = (int*)(ss + 128); // 64 ints
  float* pool = (float*)(cnt + 64);  // 64*64

  float* out = (float*)d_out;  // FLOAT32 output

  // zero bufB .. pool end in one shot (covers agg1, deg, bns, ss, cnt, pool)
  size_t zbytes = (size_t)((char*)(pool + GGRAPHS * 64) - (char*)bufB);
  hipMemsetAsync(bufB, 0, zbytes, stream);

  int blk = 256;
  int gridE = (E + blk - 1) / blk;
  int gridN = (n + blk - 1) / blk;
  int gridRows = (n + 3) / 4;
  int gridEdgeCh = (int)(((long long)E * 64 + blk - 1) / blk);
  int gridPool = (n + 63) / 64;

  deg_kernel<<<gridE, blk, 0, stream>>>(dstp, (int*)dinv, E, n);
  cnt_kernel<<<128, blk, 0, stream>>>(batch, cnt, n);
  dinv_kernel<<<gridN, blk, 0, stream>>>((int*)dinv, n);
  mm64_kernel<<<gridRows, blk, 0, stream>>>(x, W1, bufA, n);
  edge_scatter_kernel<<<gridEdgeCh, blk, 0, stream>>>(src, dstp, dinv, bufA, bufB, E, n);
  selfloop_bias_bnstats_kernel<<<512, blk, 0, stream>>>(bufA, dinv, b1, bufB, bns, n);
  bn_final_kernel<<<1, 64, 0, stream>>>(bns, gamma, beta, ss, n);
  bn_elu_mm64_kernel<<<gridRows, blk, 0, stream>>>(bufB, W2, ss, bufA, n);
  hipMemsetAsync(bufB, 0, nf * sizeof(float), stream);
  edge_scatter_kernel<<<gridEdgeCh, blk, 0, stream>>>(src, dstp, dinv, bufA, bufB, E, n);
  out_pool_kernel<<<gridPool, blk, 0, stream>>>(bufA, bufB, dinv, b2, batch, pool, out, n);
  pool_final_kernel<<<(GGRAPHS * 64) / blk, blk, 0, stream>>>(pool, cnt, out + nf);
}